// Round 8
// baseline (120.773 us; speedup 1.0000x reference)
//
#include <hip/hip_runtime.h>
#include <hip/hip_bf16.h>
#include <math.h>

#define Bsz 8
#define Nsz 1024
#define FIN 128
#define Hh  4
#define FO  64
#define COLS 256   // Hh*FO
#define TN  16
#define TM  32
#define BN  (Bsz*Nsz)
#define SHIFT 12.0f
#define HSTR 40    // ushort stride per c-row of attn h-tile (32 data + 8 pad)
#define PSTR 136   // ushort stride per r-row of p-tile (128 data + 8 pad)
#define MSPLIT 4   // m-dimension split across blockIdx.z
#define TPS  8     // tiles per split = 32/MSPLIT

typedef __attribute__((ext_vector_type(8))) short short8;
typedef __attribute__((ext_vector_type(4))) float f32x4;
typedef __attribute__((ext_vector_type(2))) float f32x2;

static __device__ inline ushort f2bf(float f) {           // RNE float->bf16
    uint u = __float_as_uint(f);
    u += 0x7FFFu + ((u >> 16) & 1u);
    return (ushort)(u >> 16);
}
static __device__ inline uint cvt_pk2(float lo, float hi) {  // packed RNE pair -> bf16x2 bits
    union { __hip_bfloat162 h; uint u; } cv;
    cv.h = __float22bfloat162_rn(float2{lo, hi});
    return cv.u;
}

// ---------------- prep: Wt[n][k] = bf16(W[k][n]) ----------------
__global__ __launch_bounds__(256) void gat_prep(const float* __restrict__ W,
                                                ushort* __restrict__ Wt)
{
    const int g = blockIdx.x * 256 + threadIdx.x;   // 0..2047
    const int n = g >> 3, kc = (g & 7) * 16;
    ushort u[16];
    #pragma unroll
    for (int i = 0; i < 16; i++) u[i] = f2bf(W[(kc + i) * COLS + n]);
    int4* dst = (int4*)(Wt + n * FIN + kc);
    dst[0] = ((int4*)u)[0];
    dst[1] = ((int4*)u)[1];
}

// ---------------- Kernel A: h = x@W via MFMA, no LDS, no barrier (R5-verified) ----------
__global__ __launch_bounds__(256) void gat_proj(
    const float* __restrict__ x, const ushort* __restrict__ Wt,
    const float* __restrict__ a, ushort* __restrict__ h_gB,
    float* __restrict__ es_g, float* __restrict__ ed_g)
{
    const int j    = threadIdx.x;
    const int w    = j >> 6, lane = j & 63, quad = lane >> 4, n16 = lane & 15;
    const int b    = blockIdx.x >> 6, mt16 = blockIdx.x & 63;
    const long rowbase = (long)b * Nsz + mt16 * 16;

    // B fragments (16 x b128 from Wt, L2-hot)
    short8 bfr[4][4];
    #pragma unroll
    for (int kk = 0; kk < 4; kk++)
        #pragma unroll
        for (int c4 = 0; c4 < 4; c4++)
            bfr[kk][c4] = *(const short8*)(Wt + (w*64 + c4*16 + n16) * FIN + kk*32 + quad*8);

    // A fragments direct from x
    short8 af[4];
    const float* xr = x + (rowbase + n16) * FIN + quad * 8;
    #pragma unroll
    for (int kk = 0; kk < 4; kk++) {
        float4 v0 = *(const float4*)(xr + kk*32);
        float4 v1 = *(const float4*)(xr + kk*32 + 4);
        union { uint u[4]; short8 s; } pk;
        pk.u[0] = cvt_pk2(v0.x, v0.y); pk.u[1] = cvt_pk2(v0.z, v0.w);
        pk.u[2] = cvt_pk2(v1.x, v1.y); pk.u[3] = cvt_pk2(v1.z, v1.w);
        af[kk] = pk.s;
    }

    f32x4 acc[4];
    #pragma unroll
    for (int c4 = 0; c4 < 4; c4++)
        #pragma unroll
        for (int r = 0; r < 4; r++) acc[c4][r] = 0.f;

    #pragma unroll
    for (int kk = 0; kk < 4; kk++)
        #pragma unroll
        for (int c4 = 0; c4 < 4; c4++)
            acc[c4] = __builtin_amdgcn_mfma_f32_16x16x32_bf16(af[kk], bfr[kk][c4], acc[c4], 0, 0, 0);

    // ---- h_gB store: [b][mt=row/32][c][k=row%32] bf16 (R5-verified layout) ----
    const int mtile = mt16 >> 1;
    const int kbase = (mt16 & 1) * 16 + quad * 4;
    #pragma unroll
    for (int c4 = 0; c4 < 4; c4++) {
        uint2 pk;
        pk.x = cvt_pk2(acc[c4][0], acc[c4][1]);
        pk.y = cvt_pk2(acc[c4][2], acc[c4][3]);
        const int c = w*64 + c4*16 + n16;
        *(uint2*)(h_gB + (((long)(b*32 + mtile) * COLS + c) * 32 + kbase)) = pk;
    }

    // ---- es/ed from fp32 accumulators ----
    float aS[4], aD[4];
    #pragma unroll
    for (int c4 = 0; c4 < 4; c4++) {
        aS[c4] = a[w * (2*FO) + c4*16 + n16];
        aD[c4] = a[w * (2*FO) + FO + c4*16 + n16];
    }
    #pragma unroll
    for (int reg = 0; reg < 4; reg++) {
        float ps = 0.f, pd = 0.f;
        #pragma unroll
        for (int c4 = 0; c4 < 4; c4++) {
            ps = fmaf(acc[c4][reg], aS[c4], ps);
            pd = fmaf(acc[c4][reg], aD[c4], pd);
        }
        #pragma unroll
        for (int off = 1; off < 16; off <<= 1) {
            ps += __shfl_xor(ps, off, 64);
            pd += __shfl_xor(pd, off, 64);
        }
        if (n16 == 0) {
            const long row = rowbase + quad*4 + reg;
            es_g[(long)w * BN + row] = ps;
            ed_g[(long)w * BN + row] = pd;
        }
    }
}

// ---------------- Kernel B: R5 structure, m-split over blockIdx.z, raw partials out ----
// grid (64, 8, MSPLIT), 256 thr. Block handles TPS=8 tiles of its m-window.
// All R5-verified macros unchanged; epilogue writes raw acc (C-layout) + partial l.
__global__ __launch_bounds__(256, 2) void gat_attn(
    const int* __restrict__ adj, const ushort* __restrict__ h_gB,
    const float* __restrict__ es_g, const float* __restrict__ ed_g,
    float* __restrict__ oP, float* __restrict__ lP)
{
    __shared__ ushort hT[2][COLS * HSTR];   // 2 x 20 KB
    __shared__ ushort pT[2][TN * PSTR];     // 2 x 4.25 KB

    const int j    = threadIdx.x;
    const int w    = j >> 6, lane = j & 63, quad = lane >> 4, n16 = lane & 15;
    const int mi   = lane & 31, hh = lane >> 5;
    const int b    = blockIdx.y;
    const int half = blockIdx.z;
    const int n0   = blockIdx.x * TN;
    const long rowb = (long)b * Nsz + n0;

    f32x2 es2[4];
    #pragma unroll
    for (int r4 = 0; r4 < 4; r4++)
        es2[r4] = (f32x2){ es_g[(long)(hh*2 + 0) * BN + rowb + w*4 + r4],
                           es_g[(long)(hh*2 + 1) * BN + rowb + w*4 + r4] };

    f32x4 acc[4];
    #pragma unroll
    for (int c4 = 0; c4 < 4; c4++)
        #pragma unroll
        for (int r = 0; r < 4; r++) acc[c4][r] = 0.f;

    f32x2 l2p[4];
    #pragma unroll
    for (int r4 = 0; r4 < 4; r4++) l2p[r4] = (f32x2){0.f, 0.f};

    short8 hr[2][4]; int ar[2][4]; f32x2 edr[2];
    const short8* hb8 = (const short8*)h_gB;

#define PREFETCH(t, S) {                                                        \
    const int gt_ = half * TPS + (t);                                           \
    const short8* g = hb8 + (long)(b*32 + gt_) * 1024;                          \
    hr[S][0] = g[j];     hr[S][1] = g[j+256];                                   \
    hr[S][2] = g[j+512]; hr[S][3] = g[j+768];                                   \
    const int m0p = gt_ * TM;                                                   \
    _Pragma("unroll")                                                           \
    for (int r4 = 0; r4 < 4; r4++)                                              \
        ar[S][r4] = adj[(rowb + w*4 + r4) * (long)Nsz + m0p + mi];              \
    edr[S] = (f32x2){ ed_g[(long)(hh*2 + 0) * BN + (long)b * Nsz + m0p + mi],   \
                      ed_g[(long)(hh*2 + 1) * BN + (long)b * Nsz + m0p + mi] }; }

#define STAGE(buf, S) {                                                         \
    _Pragma("unroll")                                                           \
    for (int i = 0; i < 4; i++) {                                               \
        const int s = j + 256*i;                                                \
        *(short8*)(&hT[buf][(s >> 2) * HSTR + (s & 3) * 8]) = hr[S][i]; } }

#define PHASE_S(buf, S) {                                                       \
    _Pragma("unroll")                                                           \
    for (int r4 = 0; r4 < 4; r4++) {                                            \
        f32x2 s2 = es2[r4] + edr[S];                                            \
        s2 = __builtin_elementwise_max(s2, s2 * 0.2f);                          \
        s2 = s2 - SHIFT;                                                        \
        float e0 = __expf(s2.x), e1 = __expf(s2.y);                             \
        const bool keep = ar[S][r4] > 0;                                        \
        uint pk = cvt_pk2(keep ? e0 : 0.f, keep ? e1 : 0.f);                    \
        pT[buf][(w*4 + r4) * PSTR + (hh*2 + 0) * TM + mi] = (ushort)(pk & 0xFFFFu); \
        pT[buf][(w*4 + r4) * PSTR + (hh*2 + 1) * TM + mi] = (ushort)(pk >> 16); \
        l2p[r4] += (f32x2){ __uint_as_float(pk << 16),                          \
                            __uint_as_float(pk & 0xFFFF0000u) }; } }

#define PHASE_A(buf) {                                                          \
    short8 afp = *(const short8*)(&pT[buf][n16 * PSTR + w * TM + quad * 8]);    \
    _Pragma("unroll")                                                           \
    for (int c4 = 0; c4 < 4; c4++) {                                            \
        short8 bfv = *(const short8*)(&hT[buf][(w*64 + c4*16 + n16) * HSTR + quad * 8]); \
        acc[c4] = __builtin_amdgcn_mfma_f32_16x16x32_bf16(afp, bfv, acc[c4], 0, 0, 0); } }

    // prologue (R5 pattern, TPS tiles)
    PREFETCH(0, 0); PREFETCH(1, 1);
    STAGE(0, 0); PHASE_S(0, 0);
    PREFETCH(2, 0);
    __syncthreads();

    for (int tt = 0; tt < TPS/2; tt++) {
        const int t0 = 2 * tt;
        if (t0 < TPS - 1) {
            STAGE(1, 1); PHASE_S(1, 1);
            if (t0 + 3 < TPS) PREFETCH(t0 + 3, 1);
        }
        PHASE_A(0);
        __syncthreads();
        if (t0 + 1 < TPS - 1) {
            STAGE(0, 0); PHASE_S(0, 0);
            if (t0 + 4 < TPS) PREFETCH(t0 + 4, 0);
        }
        PHASE_A(1);
        __syncthreads();
    }

    // ---- epilogue: raw partials, no LDS, no normalization ----
    const long pbase = (long)((half * Bsz + b) * 64 + blockIdx.x);
    #pragma unroll
    for (int r4 = 0; r4 < 4; r4++)
        #pragma unroll
        for (int ii = 0; ii < 2; ii++) {
            float lp = ii ? l2p[r4].y : l2p[r4].x;
            #pragma unroll
            for (int off = 1; off < 32; off <<= 1) lp += __shfl_xor(lp, off, 64);
            if (mi == 0)
                lP[pbase * (Hh*TN) + (hh*2 + ii) * TN + w*4 + r4] = lp;
        }
    #pragma unroll
    for (int c4 = 0; c4 < 4; c4++)
        #pragma unroll
        for (int reg = 0; reg < 4; reg++)
            oP[pbase * (Hh*TN*FO) + ((w*TN + quad*4 + reg) * FO) + c4*16 + n16] = acc[c4][reg];
#undef PREFETCH
#undef STAGE
#undef PHASE_S
#undef PHASE_A
}

// ---------------- combine: sum m-splits, normalize, mean heads ----------------
// grid (64, 8), 256 thr; block = 16 rows x 64 f.
__global__ __launch_bounds__(256) void gat_comb(
    const float* __restrict__ oP, const float* __restrict__ lP,
    float* __restrict__ out)
{
    const int nt = blockIdx.x, b = blockIdx.y;
    const int j = threadIdx.x;
    #pragma unroll
    for (int k = 0; k < 4; k++) {
        const int idx = j + k * 256;         // 0..1023
        const int r = idx >> 6, f = idx & 63;
        float sum = 0.f;
        #pragma unroll
        for (int hd = 0; hd < Hh; hd++) {
            float v = 0.f, l = 0.f;
            #pragma unroll
            for (int half = 0; half < MSPLIT; half++) {
                const long base = (long)((half * Bsz + b) * 64 + nt);
                v += oP[base * (Hh*TN*FO) + (hd*TN + r) * FO + f];
                l += lP[base * (Hh*TN)   + hd*TN + r];
            }
            sum += v / l;
        }
        out[((long)b * Nsz + nt*16 + r) * FO + f] = sum * 0.25f;
    }
}

extern "C" void kernel_launch(void* const* d_in, const int* in_sizes, int n_in,
                              void* d_out, int out_size, void* d_ws, size_t ws_size,
                              hipStream_t stream) {
    const float* x   = (const float*)d_in[0];   // (8,1024,128) f32
    const int*   adj = (const int*)d_in[1];     // (8,1024,1024) i32
    const float* W   = (const float*)d_in[2];   // (128,256) f32
    const float* a   = (const float*)d_in[3];   // (4,128) f32
    float* out = (float*)d_out;                 // (8,1024,64) f32

    // ws: Wt (64KB) | h_gB (4MB) | es (128KB) | ed (128KB) | oP (32MB) | lP (512KB)
    ushort* Wt   = (ushort*)d_ws;
    ushort* h_gB = Wt + (size_t)COLS * FIN;
    float*  es_g = (float*)(h_gB + (size_t)BN * COLS);
    float*  ed_g = es_g + (size_t)Hh * BN;
    float*  oP   = ed_g + (size_t)Hh * BN;
    float*  lP   = oP + (size_t)MSPLIT * Bsz * 64 * (Hh*TN*FO);

    gat_prep<<<dim3(8),                    dim3(256), 0, stream>>>(W, Wt);
    gat_proj<<<dim3(Bsz*Nsz/16),           dim3(256), 0, stream>>>(x, Wt, a, h_gB, es_g, ed_g);
    gat_attn<<<dim3(Nsz/TN, Bsz, MSPLIT),  dim3(256), 0, stream>>>(adj, h_gB, es_g, ed_g, oP, lP);
    gat_comb<<<dim3(Nsz/TN, Bsz),          dim3(256), 0, stream>>>(oP, lP, out);
}